// Round 2
// baseline (224.264 us; speedup 1.0000x reference)
//
#include <hip/hip_runtime.h>
#include <hip/hip_bf16.h>

#define PREFIX_N 20000
#define LEAF_N   50000
#define NONLEAF_N 50000
#define CH_N     (LEAF_N + NONLEAF_N)   /* 100000 */
#define CCOL     256
#define GK       2048
#define GM       NONLEAF_N              /* 50000 */
#define OUT_ROWS (PREFIX_N + CH_N)      /* 120000 */
#define NKT      (GK / 32)              /* 64 K-steps */

typedef float  f32x4v __attribute__((ext_vector_type(4)));
typedef __bf16 bf16x8 __attribute__((ext_vector_type(8)));
typedef short  s16x8  __attribute__((ext_vector_type(8)));

static __device__ __forceinline__ unsigned pk2(float a, float b) {
  __hip_bfloat16 ha = __float2bfloat16(a);
  __hip_bfloat16 hb = __float2bfloat16(b);
  unsigned short sa = __builtin_bit_cast(unsigned short, ha);
  unsigned short sb = __builtin_bit_cast(unsigned short, hb);
  return (unsigned)sa | ((unsigned)sb << 16);
}
static __device__ __forceinline__ uint4 pack8(const float4& x, const float4& y) {
  uint4 r;
  r.x = pk2(x.x, x.y); r.y = pk2(x.z, x.w);
  r.z = pk2(y.x, y.y); r.w = pk2(y.z, y.w);
  return r;
}

#define GLDS16(g, l) __builtin_amdgcn_global_load_lds(                      \
    (const __attribute__((address_space(1))) void*)(g),                     \
    (__attribute__((address_space(3))) void*)(l), 16, 0, 0)

// ---- W fp32 -> bf16 pre-convert (1 MB, L2-resident for the GEMM) --------
__global__ __launch_bounds__(256) void wcvt(const float* __restrict__ W,
                                            unsigned short* __restrict__ Wb) {
  int i = blockIdx.x * 256 + threadIdx.x;          // 65536 threads x 8 floats
  float4 a = ((const float4*)W)[i * 2];
  float4 b = ((const float4*)W)[i * 2 + 1];
  *(uint4*)&Wb[i * 8] = pack8(a, b);
}

// ---- rank pipeline -------------------------------------------------------
__global__ __launch_bounds__(256) void count_leaves(const int* __restrict__ ch,
                                                    int n, int* __restrict__ cnt) {
  int gi = blockIdx.x * 256 + threadIdx.x;
  int lm = (gi < n && ch[gi] < 0) ? 1 : 0;
  unsigned long long mask = __ballot(lm);
  __shared__ int wsum[4];
  int lane = threadIdx.x & 63, w = threadIdx.x >> 6;
  if (lane == 0) wsum[w] = __popcll(mask);
  __syncthreads();
  if (threadIdx.x == 0) cnt[blockIdx.x] = wsum[0] + wsum[1] + wsum[2] + wsum[3];
}

__global__ __launch_bounds__(512) void scan_blocks(const int* __restrict__ cnt,
                                                   int* __restrict__ boff, int nb) {
  __shared__ int s[512];
  int t = threadIdx.x;
  int v = (t < nb) ? cnt[t] : 0;
  s[t] = v;
  __syncthreads();
  for (int d = 1; d < 512; d <<= 1) {
    int add = (t >= d) ? s[t - d] : 0;
    __syncthreads();
    s[t] += add;
    __syncthreads();
  }
  if (t < nb) boff[t] = s[t] - v;   // exclusive scan of leaf counts
}

__global__ __launch_bounds__(256) void rank_kernel(const int* __restrict__ ch,
                                                   const int* __restrict__ boff, int n,
                                                   int* __restrict__ idx,
                                                   int* __restrict__ rowof) {
  int gi = blockIdx.x * 256 + threadIdx.x;
  int lane = threadIdx.x & 63, w = threadIdx.x >> 6;
  int lm = (gi < n && ch[gi] < 0) ? 1 : 0;
  unsigned long long mask = __ballot(lm);
  int lrank = __popcll(mask & ((1ull << lane) - 1ull));
  __shared__ int wcnt[4];
  if (lane == 63) wcnt[w] = lrank + lm;
  __syncthreads();
  int woff = 0;
  for (int i = 0; i < w; ++i) woff += wcnt[i];
  if (gi < n) {
    int rl = boff[blockIdx.x] + woff + lrank;
    if (lm) {
      idx[gi] = rl;
    } else {
      int rn = gi - rl;
      idx[gi] = LEAF_N + rn;
      rowof[rn] = gi;
    }
  }
}

// ---- prefix + leaf copies ------------------------------------------------
__global__ __launch_bounds__(256) void copy_rows(const float* __restrict__ x,
                                                 const int* __restrict__ idx,
                                                 float* __restrict__ out) {
  int row = blockIdx.x * 4 + (threadIdx.x >> 6);
  if (row >= OUT_ROWS) return;
  int lane = threadIdx.x & 63;
  const float* src;
  if (row < PREFIX_N) {
    src = x + (size_t)row * CCOL;
  } else {
    int id = idx[row - PREFIX_N];
    if (id >= LEAF_N) return;                    // nonleaf: GEMM writes it
    src = x + (size_t)(PREFIX_N + id) * CCOL;
  }
  float4 v = ((const float4*)src)[lane];
  ((float4*)(out + (size_t)row * CCOL))[lane] = v;
}

// ---- GEMM: out[PREFIX+rowof[m]] = A[m,:] @ Wb^T --------------------------
// BM=128 BN=256 BK=32, 512 threads = 8 waves (2m x 4n), wave tile 64x64.
// Double-buffered LDS; raw s_barrier + FIFO-vmcnt 2-deep pipeline:
//   iter n: read frags(tile n) | lgkm0+bar | cvt+ds_write A(n+1) [vmcnt wait
//   retires B(n+1) glds too: issued older] | glds B(n+2) | load A(n+2) |
//   MFMA | lgkm0+bar.  New issues happen AFTER the wait -> never drained.
__global__ __launch_bounds__(512) void gemm_kernel(const float* __restrict__ A,
                                                   const unsigned short* __restrict__ Wb,
                                                   const int* __restrict__ rowof,
                                                   float* __restrict__ out) {
  __shared__ unsigned short Abuf[2][128 * 32];   // 64-B rows, XOR-swizzled chunks
  __shared__ unsigned short Bbuf[2][256 * 32];
  __shared__ int tgt[128];

  const int tid  = threadIdx.x;
  const int lane = tid & 63;
  const int w    = tid >> 6;
  const int wm   = w >> 2;          // 0..1
  const int wn   = w & 3;           // 0..3
  const int lr   = lane & 15, lq = lane >> 4;
  const int tile_m = blockIdx.x;

  if (tid < 128) {
    int m = tile_m * 128 + tid;
    tgt[tid] = (m < GM) ? (PREFIX_N + rowof[m]) : -1;
  }

  // A staging: thread -> row tid>>2, fp32 chunk (tid&3)*8 floats (32 B)
  const int ar = tid >> 2;
  const int ac = (tid & 3) * 8;
  int agr = tile_m * 128 + ar;
  if (agr >= GM) agr = GM - 1;
  const float* aptr = A + (size_t)agr * GK + ac;
  // A LDS write slot (bf16 16-B chunk, swizzled)
  const int awidx = ar * 32 + (((tid & 3) ^ ((ar >> 1) & 3)) << 3);

  // B glds: issue i covers rows i*128 + w*16 + (lane>>2), chunk lane&3.
  // Source pre-swizzled so linear LDS dest holds swizzled layout (m173).
  const int brow0 = (w << 4) + (lane >> 2);
  const int bch0  = (lane & 3) ^ ((brow0 >> 1) & 3);
  const int brow1 = brow0 + 128;
  const int bch1  = (lane & 3) ^ ((brow1 >> 1) & 3);
  const char* bsrc0 = (const char*)Wb + (size_t)brow0 * (GK * 2) + (bch0 << 4);
  const char* bsrc1 = (const char*)Wb + (size_t)brow1 * (GK * 2) + (bch1 << 4);
  char* bd0_0 = (char*)&Bbuf[0][0] + tid * 16;
  char* bd1_0 = bd0_0 + 8192;
  char* bd0_1 = (char*)&Bbuf[1][0] + tid * 16;
  char* bd1_1 = bd0_1 + 8192;

  // per-lane frag LDS indices (shorts), invariant across K
  int aidx[4], bidx[4];
#pragma unroll
  for (int fm = 0; fm < 4; ++fm) {
    int row = wm * 64 + fm * 16 + lr;
    aidx[fm] = row * 32 + ((lq ^ ((row >> 1) & 3)) << 3);
  }
#pragma unroll
  for (int fn = 0; fn < 4; ++fn) {
    int row = wn * 64 + fn * 16 + lr;
    bidx[fn] = row * 32 + ((lq ^ ((row >> 1) & 3)) << 3);
  }

  f32x4v acc[4][4] = {};
  float4 rAa0, rAa1, rAb0, rAb1;

  // ---- prologue: B(0),A(0),B(1),A(1) issued; stage tile 0 ----
  GLDS16(bsrc0, bd0_0); GLDS16(bsrc1, bd1_0);                  // B(0)
  rAa0 = ((const float4*)aptr)[0]; rAa1 = ((const float4*)aptr)[1];  // A(0)
  GLDS16(bsrc0 + 64, bd0_1); GLDS16(bsrc1 + 64, bd1_1);        // B(1)
  rAb0 = ((const float4*)(aptr + 32))[0]; rAb1 = ((const float4*)(aptr + 32))[1];
  *(uint4*)&Abuf[0][awidx] = pack8(rAa0, rAa1);  // vmcnt wait on A(0) retires B(0)
  asm volatile("s_waitcnt lgkmcnt(0)" ::: "memory");
  __builtin_amdgcn_s_barrier();

#define GBODY(n_, CUR, RAc0, RAc1, RAl0, RAl1, BD0, BD1)                     \
  {                                                                          \
    s16x8 af[4], bf[4];                                                      \
    _Pragma("unroll") for (int fm = 0; fm < 4; ++fm)                         \
        af[fm] = *(const s16x8*)&Abuf[CUR][aidx[fm]];                        \
    _Pragma("unroll") for (int fn = 0; fn < 4; ++fn)                         \
        bf[fn] = *(const s16x8*)&Bbuf[CUR][bidx[fn]];                        \
    asm volatile("s_waitcnt lgkmcnt(0)" ::: "memory");                       \
    __builtin_amdgcn_s_barrier();                                            \
    if ((n_) + 1 < NKT)                                                      \
      *(uint4*)&Abuf[CUR ^ 1][awidx] = pack8(RAc0, RAc1);                    \
    if ((n_) + 2 < NKT) {                                                    \
      GLDS16(bsrc0 + ((n_) + 2) * 64, BD0);                                  \
      GLDS16(bsrc1 + ((n_) + 2) * 64, BD1);                                  \
      RAl0 = ((const float4*)(aptr + ((n_) + 2) * 32))[0];                   \
      RAl1 = ((const float4*)(aptr + ((n_) + 2) * 32))[1];                   \
    }                                                                        \
    _Pragma("unroll") for (int fm = 0; fm < 4; ++fm)                         \
      _Pragma("unroll") for (int fn = 0; fn < 4; ++fn)                       \
          acc[fm][fn] = __builtin_amdgcn_mfma_f32_16x16x32_bf16(             \
              __builtin_bit_cast(bf16x8, af[fm]),                            \
              __builtin_bit_cast(bf16x8, bf[fn]), acc[fm][fn], 0, 0, 0);     \
    asm volatile("s_waitcnt lgkmcnt(0)" ::: "memory");                       \
    __builtin_amdgcn_s_barrier();                                            \
  }

#pragma unroll 1
  for (int n = 0; n < NKT; n += 2) {
    GBODY(n,     0, rAb0, rAb1, rAa0, rAa1, bd0_0, bd1_0);
    GBODY(n + 1, 1, rAa0, rAa1, rAb0, rAb1, bd0_1, bd1_1);
  }
#undef GBODY

  // ---- epilogue: scatter rows ----
#pragma unroll
  for (int fm = 0; fm < 4; ++fm) {
    int mlb = wm * 64 + fm * 16 + lq * 4;
    int t0 = tgt[mlb + 0], t1 = tgt[mlb + 1], t2 = tgt[mlb + 2], t3 = tgt[mlb + 3];
#pragma unroll
    for (int fn = 0; fn < 4; ++fn) {
      int col = wn * 64 + fn * 16 + lr;
      if (t0 >= 0) out[(size_t)t0 * CCOL + col] = acc[fm][fn][0];
      if (t1 >= 0) out[(size_t)t1 * CCOL + col] = acc[fm][fn][1];
      if (t2 >= 0) out[(size_t)t2 * CCOL + col] = acc[fm][fn][2];
      if (t3 >= 0) out[(size_t)t3 * CCOL + col] = acc[fm][fn][3];
    }
  }
}

extern "C" void kernel_launch(void* const* d_in, const int* in_sizes, int n_in,
                              void* d_out, int out_size, void* d_ws, size_t ws_size,
                              hipStream_t stream) {
  const float* x        = (const float*)d_in[0];
  const float* wts      = (const float*)d_in[1];   // (256,256,8) == row-major (256,2048)
  const int*   children = (const int*)d_in[2];
  float*       out      = (float*)d_out;

  int* wsp   = (int*)d_ws;
  int* cnt   = wsp;                 // 391
  int* boff  = wsp + 512;           // 391
  int* idx   = wsp + 1024;          // 100000
  int* rowof = wsp + 1024 + CH_N;   // 50000
  unsigned short* Wb = (unsigned short*)((char*)d_ws + (1 << 20));  // 1 MB bf16 W

  const int nb = (CH_N + 255) / 256;   // 391

  wcvt<<<256, 256, 0, stream>>>(wts, Wb);
  count_leaves<<<nb, 256, 0, stream>>>(children, CH_N, cnt);
  scan_blocks<<<1, 512, 0, stream>>>(cnt, boff, nb);
  rank_kernel<<<nb, 256, 0, stream>>>(children, boff, CH_N, idx, rowof);

  copy_rows<<<(OUT_ROWS + 3) / 4, 256, 0, stream>>>(x, idx, out);

  const float* A = x + (size_t)(PREFIX_N + LEAF_N) * CCOL;
  gemm_kernel<<<(GM + 127) / 128, 512, 0, stream>>>(A, Wb, rowof, out);
}

// Round 3
// 216.968 us; speedup vs baseline: 1.0336x; 1.0336x over previous
//
#include <hip/hip_runtime.h>
#include <hip/hip_bf16.h>

#define PREFIX_N 20000
#define LEAF_N   50000
#define NONLEAF_N 50000
#define CH_N     (LEAF_N + NONLEAF_N)   /* 100000 */
#define CCOL     256
#define GK       2048
#define GM       NONLEAF_N              /* 50000 */
#define OUT_ROWS (PREFIX_N + CH_N)      /* 120000 */
#define BM       64
#define BKT      64                     /* K per LDS tile */
#define NKT      (GK / BKT)             /* 32 K-steps */
#define TILES    ((GM + BM - 1) / BM)   /* 782 */
#define COPYROWS (PREFIX_N + LEAF_N)    /* 70000 */
#define COPYBLK  ((COPYROWS + 3) / 4)   /* 17500 */

typedef float  f32x4v __attribute__((ext_vector_type(4)));
typedef __bf16 bf16x8 __attribute__((ext_vector_type(8)));
typedef short  s16x8  __attribute__((ext_vector_type(8)));

static __device__ __forceinline__ unsigned pk2(float a, float b) {
  __hip_bfloat16 ha = __float2bfloat16(a);
  __hip_bfloat16 hb = __float2bfloat16(b);
  unsigned short sa = __builtin_bit_cast(unsigned short, ha);
  unsigned short sb = __builtin_bit_cast(unsigned short, hb);
  return (unsigned)sa | ((unsigned)sb << 16);
}
static __device__ __forceinline__ uint4 pack8(const float4& x, const float4& y) {
  uint4 r;
  r.x = pk2(x.x, x.y); r.y = pk2(x.z, x.w);
  r.z = pk2(y.x, y.y); r.w = pk2(y.z, y.w);
  return r;
}

// ---- prep: W fp32->bf16 (blocks 0..255) + leaf count (blocks 256..646) ---
__global__ __launch_bounds__(256) void prep_kernel(const float* __restrict__ W,
                                                   unsigned short* __restrict__ Wb,
                                                   const int* __restrict__ ch,
                                                   int* __restrict__ cnt) {
  if (blockIdx.x < 256) {
    int i = blockIdx.x * 256 + threadIdx.x;        // 65536 threads x 8 floats
    float4 a = ((const float4*)W)[i * 2];
    float4 b = ((const float4*)W)[i * 2 + 1];
    *(uint4*)&Wb[i * 8] = pack8(a, b);
  } else {
    int blk = blockIdx.x - 256;
    int gi = blk * 256 + threadIdx.x;
    int lm = (gi < CH_N && ch[gi] < 0) ? 1 : 0;
    unsigned long long mask = __ballot(lm);
    __shared__ int wsum[4];
    int lane = threadIdx.x & 63, w = threadIdx.x >> 6;
    if (lane == 0) wsum[w] = __popcll(mask);
    __syncthreads();
    if (threadIdx.x == 0) cnt[blk] = wsum[0] + wsum[1] + wsum[2] + wsum[3];
  }
}

__global__ __launch_bounds__(512) void scan_blocks(const int* __restrict__ cnt,
                                                   int* __restrict__ boff, int nb) {
  __shared__ int s[512];
  int t = threadIdx.x;
  int v = (t < nb) ? cnt[t] : 0;
  s[t] = v;
  __syncthreads();
  for (int d = 1; d < 512; d <<= 1) {
    int add = (t >= d) ? s[t - d] : 0;
    __syncthreads();
    s[t] += add;
    __syncthreads();
  }
  if (t < nb) boff[t] = s[t] - v;   // exclusive scan of leaf counts
}

__global__ __launch_bounds__(256) void rank_kernel(const int* __restrict__ ch,
                                                   const int* __restrict__ boff, int n,
                                                   int* __restrict__ rowof,
                                                   int* __restrict__ leafof) {
  int gi = blockIdx.x * 256 + threadIdx.x;
  int lane = threadIdx.x & 63, w = threadIdx.x >> 6;
  int lm = (gi < n && ch[gi] < 0) ? 1 : 0;
  unsigned long long mask = __ballot(lm);
  int lrank = __popcll(mask & ((1ull << lane) - 1ull));
  __shared__ int wcnt[4];
  if (lane == 63) wcnt[w] = lrank + lm;
  __syncthreads();
  int woff = 0;
  for (int i = 0; i < w; ++i) woff += wcnt[i];
  if (gi < n) {
    int rl = boff[blockIdx.x] + woff + lrank;   // leaves strictly before gi
    if (lm) leafof[rl] = gi;                    // leaf rank -> child position
    else    rowof[gi - rl] = gi;                // nonleaf rank -> child position
  }
}

// ---- main: GEMM tiles (blocks < TILES) + row copies (blocks >= TILES) ----
// GEMM: BM=64, BN=256(full), BK=64; 256 thr = 4 waves, wave-tile 64x64.
// A staged in dbuf LDS (pad 72 shorts: conflict-free r/w); B read directly
// from L2-resident bf16 W; one barrier per K-step.
__global__ __launch_bounds__(256, 3) void main_kernel(const float* __restrict__ x,
                                                      const float* __restrict__ A,
                                                      const unsigned short* __restrict__ Wb,
                                                      const int* __restrict__ rowof,
                                                      const int* __restrict__ leafof,
                                                      float* __restrict__ out) {
  __shared__ unsigned short Al[2][BM * 72];
  __shared__ int tgt[BM];

  const int tid  = threadIdx.x;
  const int lane = tid & 63;

  if (blockIdx.x >= TILES) {                      // ---- copy path ----
    int j = (blockIdx.x - TILES) * 4 + (tid >> 6);
    if (j >= COPYROWS) return;
    const float* src;
    float* dst;
    if (j < PREFIX_N) {
      src = x + (size_t)j * CCOL;
      dst = out + (size_t)j * CCOL;
    } else {
      int r = j - PREFIX_N;                       // leaf rank r
      src = x + (size_t)(PREFIX_N + r) * CCOL;    // x_leaf[r]
      dst = out + (size_t)(PREFIX_N + leafof[r]) * CCOL;
    }
    ((float4*)dst)[lane] = ((const float4*)src)[lane];
    return;
  }

  // ---- GEMM path ----
  const int wn = tid >> 6;                        // 0..3: N-quadrant
  const int lr = lane & 15, lq = lane >> 4;
  const int tile = blockIdx.x;

  if (tid < BM) {
    int m = tile * BM + tid;
    tgt[tid] = (m < GM) ? (PREFIX_N + rowof[m]) : -1;
  }

  // A staging: row ar = tid>>2 (0..63), 16 floats at col (tid&3)*16
  const int ar = tid >> 2;
  const int ac = (tid & 3) * 16;
  int agr = tile * BM + ar;
  if (agr >= GM) agr = GM - 1;                    // clamp (stores predicated)
  const float* aptr = A + (size_t)agr * GK + ac;
  const int aw = ar * 72 + ac;                    // LDS short index

  // B fragment base pointers (global, L2-resident): row = wn*64+fn*16+lr
  const unsigned short* bbase[4];
#pragma unroll
  for (int fn = 0; fn < 4; ++fn)
    bbase[fn] = Wb + (size_t)(wn * 64 + fn * 16 + lr) * GK + lq * 8;

  // A fragment LDS indices: row = fm*16+lr
  int aidx[4];
#pragma unroll
  for (int fm = 0; fm < 4; ++fm)
    aidx[fm] = (fm * 16 + lr) * 72 + lq * 8;

  f32x4v acc[4][4] = {};
  float4 r0, r1, r2, r3;
  r0 = ((const float4*)aptr)[0]; r1 = ((const float4*)aptr)[1];
  r2 = ((const float4*)aptr)[2]; r3 = ((const float4*)aptr)[3];

  int cur = 0;
#pragma unroll 1
  for (int kt = 0; kt < NKT; ++kt) {
    // publish A(kt) into LDS[cur]
    *(uint4*)&Al[cur][aw]     = pack8(r0, r1);
    *(uint4*)&Al[cur][aw + 8] = pack8(r2, r3);
    __syncthreads();

    if (kt + 1 < NKT) {                           // issue A(kt+1) early;
      const float* p = aptr + (kt + 1) * BKT;     // consumed next iteration
      r0 = ((const float4*)p)[0]; r1 = ((const float4*)p)[1];
      r2 = ((const float4*)p)[2]; r3 = ((const float4*)p)[3];
    }

#pragma unroll
    for (int ks = 0; ks < 2; ++ks) {
      s16x8 af[4], bf[4];
#pragma unroll
      for (int fm = 0; fm < 4; ++fm)
        af[fm] = *(const s16x8*)&Al[cur][aidx[fm] + ks * 32];
#pragma unroll
      for (int fn = 0; fn < 4; ++fn)
        bf[fn] = *(const s16x8*)&bbase[fn][kt * BKT + ks * 32];
#pragma unroll
      for (int fm = 0; fm < 4; ++fm)
#pragma unroll
        for (int fn = 0; fn < 4; ++fn)
          acc[fm][fn] = __builtin_amdgcn_mfma_f32_16x16x32_bf16(
              __builtin_bit_cast(bf16x8, af[fm]),
              __builtin_bit_cast(bf16x8, bf[fn]),
              acc[fm][fn], 0, 0, 0);
    }
    cur ^= 1;
  }

  // epilogue: scatter rows (C/D: col=lane&15, row=(lane>>4)*4+reg)
#pragma unroll
  for (int fm = 0; fm < 4; ++fm) {
    int mlb = fm * 16 + lq * 4;
    int t0 = tgt[mlb + 0], t1 = tgt[mlb + 1], t2 = tgt[mlb + 2], t3 = tgt[mlb + 3];
#pragma unroll
    for (int fn = 0; fn < 4; ++fn) {
      int col = wn * 64 + fn * 16 + lr;
      if (t0 >= 0) out[(size_t)t0 * CCOL + col] = acc[fm][fn][0];
      if (t1 >= 0) out[(size_t)t1 * CCOL + col] = acc[fm][fn][1];
      if (t2 >= 0) out[(size_t)t2 * CCOL + col] = acc[fm][fn][2];
      if (t3 >= 0) out[(size_t)t3 * CCOL + col] = acc[fm][fn][3];
    }
  }
}

extern "C" void kernel_launch(void* const* d_in, const int* in_sizes, int n_in,
                              void* d_out, int out_size, void* d_ws, size_t ws_size,
                              hipStream_t stream) {
  const float* x        = (const float*)d_in[0];
  const float* wts      = (const float*)d_in[1];   // (256,256,8) == row-major (256,2048)
  const int*   children = (const int*)d_in[2];
  float*       out      = (float*)d_out;

  int* wsp    = (int*)d_ws;
  int* cnt    = wsp;                 // 391
  int* boff   = wsp + 512;           // 391
  int* rowof  = wsp + 1024;          // 50000
  int* leafof = wsp + 1024 + GM;     // 50000   (~404 KB total ints)
  unsigned short* Wb = (unsigned short*)((char*)d_ws + (1 << 20));  // 1 MB bf16 W

  const int nb = (CH_N + 255) / 256;   // 391

  prep_kernel<<<256 + nb, 256, 0, stream>>>(wts, Wb, children, cnt);
  scan_blocks<<<1, 512, 0, stream>>>(cnt, boff, nb);
  rank_kernel<<<nb, 256, 0, stream>>>(children, boff, CH_N, rowof, leafof);

  const float* A = x + (size_t)(PREFIX_N + LEAF_N) * CCOL;
  main_kernel<<<TILES + COPYBLK, 256, 0, stream>>>(x, A, Wb, rowof, leafof, out);
}